// Round 1
// 172.812 us; speedup vs baseline: 1.0176x; 1.0176x over previous
//
#include <hip/hip_runtime.h>

// Problem constants (derived at launch from in_sizes, but fixed by the reference):
// B=32, N=65536, FEAT_SUM=15, DIM_LIST={1,2,3} -> blocks of 3,5,7.
#define PSTRIDE 544  // per-batch folded-param block, in floats:
                     // [0..59]    A1 rows: 15 x {w0,w1,w2,b1}
                     // [64..303]  W2 rows: 15 x 16 (15 weights + b2 at [15])
                     // [304..543] A3 rows: 15 x 16 (15 weights + c3 at [15])

// ---------------------------------------------------------------------------
// Kernel A: build per-batch folded parameters.
//   A1 = W1 * R^T           (folds the input un-rotation into layer 1)
//   D  = blockdiag(Q1 R Q1^T, Q2 (R(x)R) Q2^T, Q3 (R(x)R(x)R) Q3^T)
//   A3 = D * W3, c3 = D * b3 (folds the output re-rotation into layer 3)
// One block per batch, tiny; staged contractions through LDS.
// ---------------------------------------------------------------------------
__global__ void prep_params(const float* __restrict__ R_,
                            const float* __restrict__ W1, const float* __restrict__ b1,
                            const float* __restrict__ W2, const float* __restrict__ b2,
                            const float* __restrict__ W3, const float* __restrict__ b3,
                            const float* __restrict__ Q1, const float* __restrict__ Q2,
                            const float* __restrict__ Q3,
                            float* __restrict__ P) {
  __shared__ float sR[9];
  __shared__ float sK2[81];    // R (x) R        [9x9]
  __shared__ float sK3[729];   // R (x) R (x) R  [27x27]
  __shared__ float sT2[45];    // K2 * Q2^T      [9x5]
  __shared__ float sT3[189];   // K3 * Q3^T      [27x7]
  __shared__ float sD1[9], sD2[25], sD3[49];

  const int b = blockIdx.x;
  const int t = threadIdx.x;
  const int bs = blockDim.x;
  const float* R = R_ + b * 9;

  if (t < 9) sR[t] = R[t];
  __syncthreads();

  for (int i = t; i < 81; i += bs) {
    int r = i / 9, c = i % 9;
    sK2[i] = sR[(r / 3) * 3 + (c / 3)] * sR[(r % 3) * 3 + (c % 3)];
  }
  for (int i = t; i < 729; i += bs) {
    int r = i / 27, c = i % 27;
    sK3[i] = sR[(r / 9) * 3 + (c / 9)] *
             sR[((r / 3) % 3) * 3 + ((c / 3) % 3)] *
             sR[(r % 3) * 3 + (c % 3)];
  }
  __syncthreads();

  for (int i = t; i < 45; i += bs) {
    int r = i / 5, q = i % 5;
    float acc = 0.f;
    for (int c = 0; c < 9; ++c) acc += sK2[r * 9 + c] * Q2[q * 9 + c];
    sT2[i] = acc;
  }
  for (int i = t; i < 189; i += bs) {
    int r = i / 7, q = i % 7;
    float acc = 0.f;
    for (int c = 0; c < 27; ++c) acc += sK3[r * 27 + c] * Q3[q * 27 + c];
    sT3[i] = acc;
  }
  __syncthreads();

  for (int i = t; i < 9; i += bs) {
    int p = i / 3, q = i % 3;
    float acc = 0.f;
    for (int ii = 0; ii < 3; ++ii)
      for (int jj = 0; jj < 3; ++jj)
        acc += Q1[p * 3 + ii] * sR[ii * 3 + jj] * Q1[q * 3 + jj];
    sD1[i] = acc;
  }
  for (int i = t; i < 25; i += bs) {
    int p = i / 5, q = i % 5;
    float acc = 0.f;
    for (int r2 = 0; r2 < 9; ++r2) acc += Q2[p * 9 + r2] * sT2[r2 * 5 + q];
    sD2[i] = acc;
  }
  for (int i = t; i < 49; i += bs) {
    int p = i / 7, q = i % 7;
    float acc = 0.f;
    for (int r2 = 0; r2 < 27; ++r2) acc += Q3[p * 27 + r2] * sT3[r2 * 7 + q];
    sD3[i] = acc;
  }
  __syncthreads();

  float* Pb = P + (size_t)b * PSTRIDE;

  // A1 rows: A1[f][j] = sum_i W1[f,i] * R[j,i];  [3] = b1[f]
  for (int f = t; f < 15; f += bs) {
    for (int j = 0; j < 3; ++j) {
      float acc = 0.f;
      for (int i2 = 0; i2 < 3; ++i2) acc += W1[f * 3 + i2] * sR[j * 3 + i2];
      Pb[f * 4 + j] = acc;
    }
    Pb[f * 4 + 3] = b1[f];
  }
  // W2 rows: row f = {W2[f,0..14], b2[f]}
  for (int i = t; i < 240; i += bs) {
    int f = i / 16, k = i % 16;
    Pb[64 + i] = (k < 15) ? W2[f * 15 + k] : b2[f];
  }
  // A3 rows: A3[f][k] = sum_q D[f,q] * W3[q,k];  [15] = sum_q D[f,q] * b3[q]
  for (int i = t; i < 240; i += bs) {
    int f = i / 16, k = i % 16;
    float acc = 0.f;
    if (f < 3) {
      for (int q = 0; q < 3; ++q) {
        float d = sD1[f * 3 + q];
        acc += d * ((k < 15) ? W3[q * 15 + k] : b3[q]);
      }
    } else if (f < 8) {
      for (int q = 0; q < 5; ++q) {
        float d = sD2[(f - 3) * 5 + q];
        acc += d * ((k < 15) ? W3[(q + 3) * 15 + k] : b3[q + 3]);
      }
    } else {
      for (int q = 0; q < 7; ++q) {
        float d = sD3[(f - 8) * 7 + q];
        acc += d * ((k < 15) ? W3[(q + 8) * 15 + k] : b3[q + 8]);
      }
    }
    Pb[304 + i] = acc;
  }
}

// ---------------------------------------------------------------------------
// Kernel B: fused pointwise MLP with folded rotations.
// v2: 2 points/thread (was 4) -> live state h1+h2 = 60 floats (was 120),
// targeting ~5 waves/SIMD (~20/CU) instead of ~3 for memory overlap.
// float2 I/O (8 B/lane, 512 B contiguous per wave-instr = full HBM lines).
// x-loads issued BEFORE the sP staging barrier so HBM latency hides under it.
// Weight rows fetched as float4 (ds_read_b128 broadcasts) into static-indexed
// register arrays.
// grid = (N/512, B), block = 256.
// ---------------------------------------------------------------------------
__global__ __launch_bounds__(256) void fused_mlp_rot(
    const float* __restrict__ x, const float* __restrict__ P,
    float* __restrict__ out, int N) {
  __shared__ float sP[PSTRIDE];
  const int b = blockIdx.y;
  const int t = threadIdx.x;

  const int n0 = (blockIdx.x * 256 + t) * 2;
  const bool act = (n0 < N);

  // Issue the 3 global loads first: their latency overlaps the LDS staging
  // and the barrier drain below.
  const float* xb = x + (size_t)b * 3 * N + n0;
  float2 xa = make_float2(0.f, 0.f), xm = xa, xc = xa;
  if (act) {
    xa = *(const float2*)(xb);
    xm = *(const float2*)(xb + N);
    xc = *(const float2*)(xb + 2 * N);
  }

  if (t < PSTRIDE / 4) {
    ((float4*)sP)[t] = ((const float4*)(P + (size_t)b * PSTRIDE))[t];
  }
  __syncthreads();

  if (!act) return;

  // Layer 1: h1 = relu(A1 * x + b1)   (A1 already includes R^T)
  float h1a[15], h1b[15];
#pragma unroll
  for (int f = 0; f < 15; ++f) {
    float4 w = ((const float4*)sP)[f];
    h1a[f] = fmaxf(fmaf(w.x, xa.x, fmaf(w.y, xm.x, fmaf(w.z, xc.x, w.w))), 0.f);
    h1b[f] = fmaxf(fmaf(w.x, xa.y, fmaf(w.y, xm.y, fmaf(w.z, xc.y, w.w))), 0.f);
  }

  // Layer 2: h2 = relu(W2 * h1 + b2)
  float h2a[15], h2b[15];
#pragma unroll
  for (int f = 0; f < 15; ++f) {
    float w[16];
#pragma unroll
    for (int q = 0; q < 4; ++q)
      ((float4*)w)[q] = ((const float4*)(sP + 64))[f * 4 + q];
    float a0 = w[15], a1 = w[15];
#pragma unroll
    for (int g = 0; g < 15; ++g) {
      a0 = fmaf(w[g], h1a[g], a0);
      a1 = fmaf(w[g], h1b[g], a1);
    }
    h2a[f] = fmaxf(a0, 0.f);
    h2b[f] = fmaxf(a1, 0.f);
  }

  // Layer 3 + rotation: out = A3 * h2 + c3   (A3 = D*W3, c3 = D*b3)
  float* ob = out + (size_t)b * 15 * N + n0;
#pragma unroll
  for (int f = 0; f < 15; ++f) {
    float w[16];
#pragma unroll
    for (int q = 0; q < 4; ++q)
      ((float4*)w)[q] = ((const float4*)(sP + 304))[f * 4 + q];
    float a0 = w[15], a1 = w[15];
#pragma unroll
    for (int g = 0; g < 15; ++g) {
      a0 = fmaf(w[g], h2a[g], a0);
      a1 = fmaf(w[g], h2b[g], a1);
    }
    *(float2*)(ob + (size_t)f * N) = make_float2(a0, a1);
  }
}

extern "C" void kernel_launch(void* const* d_in, const int* in_sizes, int n_in,
                              void* d_out, int out_size, void* d_ws, size_t ws_size,
                              hipStream_t stream) {
  const float* x  = (const float*)d_in[0];
  const float* R  = (const float*)d_in[1];
  const float* W1 = (const float*)d_in[2];
  const float* b1 = (const float*)d_in[3];
  const float* W2 = (const float*)d_in[4];
  const float* b2 = (const float*)d_in[5];
  const float* W3 = (const float*)d_in[6];
  const float* b3 = (const float*)d_in[7];
  const float* Q1 = (const float*)d_in[8];
  const float* Q2 = (const float*)d_in[9];
  const float* Q3 = (const float*)d_in[10];
  float* out = (float*)d_out;
  float* P   = (float*)d_ws;

  const int B = in_sizes[1] / 9;            // 32
  const int N = in_sizes[0] / (3 * B);      // 65536

  prep_params<<<dim3(B), dim3(128), 0, stream>>>(R, W1, b1, W2, b2, W3, b3,
                                                 Q1, Q2, Q3, P);

  const int chunks = (N + 511) / 512;       // 256 threads * 2 pts
  fused_mlp_rot<<<dim3(chunks, B), dim3(256), 0, stream>>>(x, P, out, N);
}